// Round 5
// baseline (127.175 us; speedup 1.0000x reference)
//
#include <hip/hip_runtime.h>
#include <math.h>

#define BATCH 128
#define DIN   1024
#define DOUT  1024
#define NB    8    // batch elements per wave: softplus amortization factor

// Native clang vector type — required by __builtin_nontemporal_load
// (HIP_vector_type float4 is a struct and is rejected).
typedef float f32x4 __attribute__((ext_vector_type(4)));

// Numerically stable softplus: max(v,0) + log1p(exp(-|v|)).
__device__ __forceinline__ float softplus_f(float v) {
    return fmaxf(v, 0.0f) + log1pf(__expf(-fabsf(v)));
}

// Round-2 structure, single delta: eps_w / eps_b are loaded NON-TEMPORAL
// (single-use stream, 512 MB = 2x L3 — caching it only churns L2/L3 and
// evicts the reusable x/mu/rho). out stores are non-temporal too.
__global__ __launch_bounds__(256) void bayes_linear_kernel(
    const float* __restrict__ x,
    const float* __restrict__ wmu,
    const float* __restrict__ wrho,
    const float* __restrict__ bmu,
    const float* __restrict__ brho,
    const float* __restrict__ epsw,
    const float* __restrict__ epsb,
    float* __restrict__ out)
{
    const int wid  = (blockIdx.x << 2) + (threadIdx.x >> 6); // global wave id
    const int lane = threadIdx.x & 63;
    const int o  = wid >> 4;             // 0..1023: 16 consecutive waves share o
    const int b0 = (wid & 15) * NB;      // 0,8,...,120

    const float4* __restrict__ mu4  = reinterpret_cast<const float4*>(wmu  + (size_t)o * DIN);
    const float4* __restrict__ rho4 = reinterpret_cast<const float4*>(wrho + (size_t)o * DIN);

    // Per-lane slice of the o-row: 16 elements = 4 x float4 (cached loads —
    // these rows are reused by 16 waves each).
    float sp[16], mu[16];
    #pragma unroll
    for (int k = 0; k < 4; ++k) {
        const int idx = lane + (k << 6);
        const float4 re = rho4[idx];
        const float4 me = mu4[idx];
        sp[4*k+0] = softplus_f(re.x);  mu[4*k+0] = me.x;
        sp[4*k+1] = softplus_f(re.y);  mu[4*k+1] = me.y;
        sp[4*k+2] = softplus_f(re.z);  mu[4*k+2] = me.z;
        sp[4*k+3] = softplus_f(re.w);  mu[4*k+3] = me.w;
    }

    float acc[NB];
    #pragma unroll
    for (int j = 0; j < NB; ++j) acc[j] = 0.0f;

    #pragma unroll
    for (int j = 0; j < NB; ++j) {
        const int b = b0 + j;
        const float4* __restrict__ x4 = reinterpret_cast<const float4*>(x + (size_t)b * DIN);
        const f32x4* __restrict__ e4 = reinterpret_cast<const f32x4*>(
            epsw + ((size_t)b * DOUT + (size_t)o) * DIN);
        float a = acc[j];
        #pragma unroll
        for (int k = 0; k < 4; ++k) {
            const int idx = lane + (k << 6);
            const float4 xe = x4[idx];                              // L2-resident (512 KB)
            const f32x4  ee = __builtin_nontemporal_load(e4 + idx); // single-use HBM stream
            a = fmaf(xe.x, fmaf(sp[4*k+0], ee.x, mu[4*k+0]), a);
            a = fmaf(xe.y, fmaf(sp[4*k+1], ee.y, mu[4*k+1]), a);
            a = fmaf(xe.z, fmaf(sp[4*k+2], ee.z, mu[4*k+2]), a);
            a = fmaf(xe.w, fmaf(sp[4*k+3], ee.w, mu[4*k+3]), a);
        }
        acc[j] = a;
    }

    // 64-lane butterfly reduction per batch element.
    #pragma unroll
    for (int j = 0; j < NB; ++j) {
        #pragma unroll
        for (int off = 32; off >= 1; off >>= 1)
            acc[j] += __shfl_xor(acc[j], off, 64);
    }

    if (lane == 0) {
        const float bsp = softplus_f(brho[o]);   // once per wave, not per b
        const float bm  = bmu[o];
        #pragma unroll
        for (int j = 0; j < NB; ++j) {
            const int b = b0 + j;
            const size_t row = (size_t)b * DOUT + o;
            const float eb = __builtin_nontemporal_load(epsb + row);
            __builtin_nontemporal_store(acc[j] + fmaf(bsp, eb, bm), out + row);
        }
    }
}

extern "C" void kernel_launch(void* const* d_in, const int* in_sizes, int n_in,
                              void* d_out, int out_size, void* d_ws, size_t ws_size,
                              hipStream_t stream) {
    const float* x    = (const float*)d_in[0];
    const float* wmu  = (const float*)d_in[1];
    const float* wrho = (const float*)d_in[2];
    const float* bmu  = (const float*)d_in[3];
    const float* brho = (const float*)d_in[4];
    const float* epsw = (const float*)d_in[5];
    const float* epsb = (const float*)d_in[6];
    float* out = (float*)d_out;

    // waves = DOUT * (BATCH/NB) = 1024 * 16 = 16384; 4 waves per 256-thread block.
    const int n_waves = DOUT * (BATCH / NB);
    const int blocks  = n_waves / 4; // 4096
    bayes_linear_kernel<<<blocks, 256, 0, stream>>>(x, wmu, wrho, bmu, brho, epsw, epsb, out);
}

// Round 6
// 120.351 us; speedup vs baseline: 1.0567x; 1.0567x over previous
//
#include <hip/hip_runtime.h>
#include <math.h>

#define BATCH 128
#define DIN   1024
#define DOUT  1024
#define NB    8      // batch elements per wave
#define B_CACHED 56  // rows b < 56 (224 MB of eps) use temporal loads -> pinned in L3;
                     // rows b >= 56 (288 MB) use non-temporal loads -> never pollute L3.

typedef float f32x4 __attribute__((ext_vector_type(4)));

// Numerically stable softplus.
__device__ __forceinline__ float softplus_f(float v) {
    return fmaxf(v, 0.0f) + log1pf(__expf(-fabsf(v)));
}

template <bool NT>
__device__ __forceinline__ void accum_rows(
    const float* __restrict__ x,
    const float* __restrict__ epsw,
    const float sp[16], const float mu[16],
    int b0, int o, int lane, float acc[NB])
{
    #pragma unroll
    for (int j = 0; j < NB; ++j) {
        const int b = b0 + j;
        const float4* __restrict__ x4 = reinterpret_cast<const float4*>(x + (size_t)b * DIN);
        const f32x4* __restrict__ e4 = reinterpret_cast<const f32x4*>(
            epsw + ((size_t)b * DOUT + (size_t)o) * DIN);
        float a = acc[j];
        #pragma unroll
        for (int k = 0; k < 4; ++k) {
            const int idx = lane + (k << 6);
            const float4 xe = x4[idx];            // L2-resident (x = 512 KB)
            f32x4 ee;
            if (NT) ee = __builtin_nontemporal_load(e4 + idx); // stream, don't cache
            else    ee = e4[idx];                              // temporal: stays in L3
            a = fmaf(xe.x, fmaf(sp[4*k+0], ee.x, mu[4*k+0]), a);
            a = fmaf(xe.y, fmaf(sp[4*k+1], ee.y, mu[4*k+1]), a);
            a = fmaf(xe.z, fmaf(sp[4*k+2], ee.z, mu[4*k+2]), a);
            a = fmaf(xe.w, fmaf(sp[4*k+3], ee.w, mu[4*k+3]), a);
        }
        acc[j] = a;
    }
}

// Round-2 structure; single delta vs round 2: eps loads are split into a
// deterministic L3-resident partition (b < 56, 224 MB, temporal) and a pure
// HBM stream (b >= 56, 288 MB, non-temporal). Eliminates L3 insertion churn
// and lowers average miss latency (the MSHR-concurrency model's only lever).
__global__ __launch_bounds__(256) void bayes_linear_kernel(
    const float* __restrict__ x,
    const float* __restrict__ wmu,
    const float* __restrict__ wrho,
    const float* __restrict__ bmu,
    const float* __restrict__ brho,
    const float* __restrict__ epsw,
    const float* __restrict__ epsb,
    float* __restrict__ out)
{
    const int wid  = (blockIdx.x << 2) + (threadIdx.x >> 6);
    const int lane = threadIdx.x & 63;
    const int o  = wid >> 4;             // 16 consecutive waves share the o-row
    const int b0 = (wid & 15) * NB;      // 0,8,...,120

    const float4* __restrict__ mu4  = reinterpret_cast<const float4*>(wmu  + (size_t)o * DIN);
    const float4* __restrict__ rho4 = reinterpret_cast<const float4*>(wrho + (size_t)o * DIN);

    float sp[16], mu[16];
    #pragma unroll
    for (int k = 0; k < 4; ++k) {
        const int idx = lane + (k << 6);
        const float4 re = rho4[idx];
        const float4 me = mu4[idx];
        sp[4*k+0] = softplus_f(re.x);  mu[4*k+0] = me.x;
        sp[4*k+1] = softplus_f(re.y);  mu[4*k+1] = me.y;
        sp[4*k+2] = softplus_f(re.z);  mu[4*k+2] = me.z;
        sp[4*k+3] = softplus_f(re.w);  mu[4*k+3] = me.w;
    }

    float acc[NB];
    #pragma unroll
    for (int j = 0; j < NB; ++j) acc[j] = 0.0f;

    // Wave-uniform branch: each wave's 8 rows are entirely on one side of 56.
    if (b0 < B_CACHED)
        accum_rows<false>(x, epsw, sp, mu, b0, o, lane, acc);
    else
        accum_rows<true>(x, epsw, sp, mu, b0, o, lane, acc);

    // 64-lane butterfly reduction per batch element.
    #pragma unroll
    for (int j = 0; j < NB; ++j) {
        #pragma unroll
        for (int off = 32; off >= 1; off >>= 1)
            acc[j] += __shfl_xor(acc[j], off, 64);
    }

    if (lane == 0) {
        const float bsp = softplus_f(brho[o]);
        const float bm  = bmu[o];
        #pragma unroll
        for (int j = 0; j < NB; ++j) {
            const int b = b0 + j;
            const size_t row = (size_t)b * DOUT + o;
            out[row] = acc[j] + fmaf(bsp, epsb[row], bm);
        }
    }
}

extern "C" void kernel_launch(void* const* d_in, const int* in_sizes, int n_in,
                              void* d_out, int out_size, void* d_ws, size_t ws_size,
                              hipStream_t stream) {
    const float* x    = (const float*)d_in[0];
    const float* wmu  = (const float*)d_in[1];
    const float* wrho = (const float*)d_in[2];
    const float* bmu  = (const float*)d_in[3];
    const float* brho = (const float*)d_in[4];
    const float* epsw = (const float*)d_in[5];
    const float* epsb = (const float*)d_in[6];
    float* out = (float*)d_out;

    const int n_waves = DOUT * (BATCH / NB); // 16384
    const int blocks  = n_waves / 4;         // 4096
    bayes_linear_kernel<<<blocks, 256, 0, stream>>>(x, wmu, wrho, bmu, brho, epsw, epsb, out);
}